// Round 2
// baseline (2494.597 us; speedup 1.0000x reference)
//
#include <hip/hip_runtime.h>

#define NN 200000
#define NE 800000
#define NG 4096
#define AD 128
#define HD 256
#define LN_EPS 1e-5f

__device__ __forceinline__ float leaky(float v){ return v > 0.f ? v : 0.2f*v; }

// bf16 round-to-nearest-even pack/unpack (no lib dependency)
__device__ __forceinline__ unsigned short f2bf(float f){
  unsigned u = __float_as_uint(f);
  return (unsigned short)((u + 0x7FFFu + ((u >> 16) & 1u)) >> 16);
}
__device__ __forceinline__ float bf2f(unsigned short h){ return __uint_as_float(((unsigned)h) << 16); }

// monotone float<->unsigned key for atomicMax-based float max
__device__ __forceinline__ unsigned fkey(float f){
  unsigned u = __float_as_uint(f);
  return (u & 0x80000000u) ? ~u : (u | 0x80000000u);
}
__device__ __forceinline__ float fdec(unsigned k){
  return (k & 0x80000000u) ? __uint_as_float(k & 0x7FFFFFFFu) : __uint_as_float(~k);
}

// ---------------- init: zero degree counters, init pooled-max keys ----------------
__global__ __launch_bounds__(256) void k_init(int* __restrict__ cur, unsigned* __restrict__ Gk){
  int i = blockIdx.x * 256 + threadIdx.x;     // grid = NG*HD/256 = 4096 blocks
  if (i < NN) cur[i] = 0;
  Gk[i] = 0x00800000u;                        // fkey(-FLT_MAX)
}

// ---------------- CSR build: count, scan, fill ----------------
__global__ __launch_bounds__(256) void k_count(const int* __restrict__ ei, int* __restrict__ cur){
  int e = blockIdx.x * 256 + threadIdx.x;     // grid*block == NE exactly
  atomicAdd(&cur[ei[NE + e]], 1);
}

__global__ __launch_bounds__(1024) void k_scan(int* __restrict__ cur, int* __restrict__ rowptr){
  __shared__ int sd[1024];
  const int t = threadIdx.x;
  const int lo = t * 196;
  const int hi = min(lo + 196, NN);
  int s = 0;
  for (int i = lo; i < hi; ++i) s += cur[i];
  sd[t] = s; __syncthreads();
  const int own = s;
  for (int off = 1; off < 1024; off <<= 1){
    int v = (t >= off) ? sd[t - off] : 0;
    __syncthreads();
    sd[t] += v;
    __syncthreads();
  }
  int prefix = sd[t] - own;                   // exclusive prefix of this thread's chunk
  for (int i = lo; i < hi; ++i){
    int v = cur[i];
    rowptr[i] = prefix;
    prefix += v;
    cur[i] = 0;                               // reset for fill phase
  }
}

__global__ __launch_bounds__(256) void k_fill(const int* __restrict__ ei,
                                              const int* __restrict__ rowptr,
                                              int* __restrict__ cur,
                                              int* __restrict__ col){
  int e = blockIdx.x * 256 + threadIdx.x;
  int s = ei[e], d = ei[NE + e];
  int pos = atomicAdd(&cur[d], 1);
  col[rowptr[d] + pos] = s;                   // after this, cur[i] == deg[i] again
}

// ---------------- fused GIN layer 1: gather(x) -> relu(.@w1+b1) -> LN(.@w2+b2) -> leaky -> bf16 H1 ----------------
__global__ __launch_bounds__(256) void k_layer1(const float* __restrict__ x,
                                                const int* __restrict__ rowptr,
                                                const int* __restrict__ deg,
                                                const int* __restrict__ col,
                                                const float* __restrict__ w1,   // 128x256
                                                const float* __restrict__ b1,
                                                const float* __restrict__ w2,   // 256x256
                                                const float* __restrict__ b2,
                                                const float* __restrict__ lng,
                                                const float* __restrict__ lnb,
                                                unsigned short* __restrict__ H1){
  __shared__ float zS[32 * AD];   // 16KB
  __shared__ float tS[32 * HD];   // 32KB
  const int tid = threadIdx.x;
  const int row0 = blockIdx.x * 32;
  const int lane = tid & 63;
  const int wv = tid >> 6;

  // gather z = x_i + sum_{j in N(i)} x_j ; lane owns 2 cols (float2)
  const float2* x2 = (const float2*)x;
  for (int rr = 0; rr < 8; ++rr){
    const int r = wv * 8 + rr;
    const int row = row0 + r;
    float2 a = x2[(size_t)row * 64 + lane];
    const int p = rowptr[row], cnt = deg[row];
    for (int q = 0; q < cnt; ++q){
      const int j = col[p + q];
      float2 b = x2[(size_t)j * 64 + lane];
      a.x += b.x; a.y += b.y;
    }
    zS[r * AD + lane * 2]     = a.x;
    zS[r * AD + lane * 2 + 1] = a.y;
  }
  __syncthreads();

  const int cx = lane;   // cols cx*4..+3
  const int rg = wv;     // rows rg*8..+7

  // GEMM-A: t = relu(z @ w1 + b1)
  float acc[8][4];
  {
    float4 b = *(const float4*)&b1[cx * 4];
    #pragma unroll
    for (int r = 0; r < 8; ++r){ acc[r][0]=b.x; acc[r][1]=b.y; acc[r][2]=b.z; acc[r][3]=b.w; }
  }
  {
    const float4* zS4 = (const float4*)zS;
    for (int k = 0; k < AD; k += 4){
      float4 w0 = *(const float4*)&w1[(size_t)(k+0)*HD + cx*4];
      float4 wA = *(const float4*)&w1[(size_t)(k+1)*HD + cx*4];
      float4 wB = *(const float4*)&w1[(size_t)(k+2)*HD + cx*4];
      float4 wC = *(const float4*)&w1[(size_t)(k+3)*HD + cx*4];
      #pragma unroll
      for (int r = 0; r < 8; ++r){
        float4 a = zS4[(rg*8 + r) * (AD/4) + (k >> 2)];
        acc[r][0] += a.x*w0.x + a.y*wA.x + a.z*wB.x + a.w*wC.x;
        acc[r][1] += a.x*w0.y + a.y*wA.y + a.z*wB.y + a.w*wC.y;
        acc[r][2] += a.x*w0.z + a.y*wA.z + a.z*wB.z + a.w*wC.z;
        acc[r][3] += a.x*w0.w + a.y*wA.w + a.z*wB.w + a.w*wC.w;
      }
    }
  }
  #pragma unroll
  for (int r = 0; r < 8; ++r){
    float4 o;
    o.x = fmaxf(acc[r][0], 0.f); o.y = fmaxf(acc[r][1], 0.f);
    o.z = fmaxf(acc[r][2], 0.f); o.w = fmaxf(acc[r][3], 0.f);
    *(float4*)&tS[(rg*8 + r) * HD + cx*4] = o;
  }
  __syncthreads();

  // GEMM-B: h = (t @ w2 + b2), then LN + leaky
  float acc2[8][4];
  {
    float4 b = *(const float4*)&b2[cx * 4];
    #pragma unroll
    for (int r = 0; r < 8; ++r){ acc2[r][0]=b.x; acc2[r][1]=b.y; acc2[r][2]=b.z; acc2[r][3]=b.w; }
  }
  {
    const float4* tS4 = (const float4*)tS;
    for (int k = 0; k < HD; k += 4){
      float4 w0 = *(const float4*)&w2[(size_t)(k+0)*HD + cx*4];
      float4 wA = *(const float4*)&w2[(size_t)(k+1)*HD + cx*4];
      float4 wB = *(const float4*)&w2[(size_t)(k+2)*HD + cx*4];
      float4 wC = *(const float4*)&w2[(size_t)(k+3)*HD + cx*4];
      #pragma unroll
      for (int r = 0; r < 8; ++r){
        float4 a = tS4[(rg*8 + r) * (HD/4) + (k >> 2)];
        acc2[r][0] += a.x*w0.x + a.y*wA.x + a.z*wB.x + a.w*wC.x;
        acc2[r][1] += a.x*w0.y + a.y*wA.y + a.z*wB.y + a.w*wC.y;
        acc2[r][2] += a.x*w0.z + a.y*wA.z + a.z*wB.z + a.w*wC.z;
        acc2[r][3] += a.x*w0.w + a.y*wA.w + a.z*wB.w + a.w*wC.w;
      }
    }
  }
  const float4 gg = *(const float4*)&lng[cx * 4];
  const float4 bb = *(const float4*)&lnb[cx * 4];
  #pragma unroll
  for (int r = 0; r < 8; ++r){
    // row lives entirely in this wave -> wave-64 butterfly for LN stats
    float s1 = acc2[r][0] + acc2[r][1] + acc2[r][2] + acc2[r][3];
    float s2 = acc2[r][0]*acc2[r][0] + acc2[r][1]*acc2[r][1]
             + acc2[r][2]*acc2[r][2] + acc2[r][3]*acc2[r][3];
    #pragma unroll
    for (int off = 32; off >= 1; off >>= 1){
      s1 += __shfl_xor(s1, off);
      s2 += __shfl_xor(s2, off);
    }
    const float m  = s1 * (1.f / HD);
    const float vr = s2 * (1.f / HD) - m * m;
    const float rs = rsqrtf(vr + LN_EPS);
    const int row = row0 + rg*8 + r;
    ushort4 hv;
    hv.x = f2bf(leaky((acc2[r][0] - m) * rs * gg.x + bb.x));
    hv.y = f2bf(leaky((acc2[r][1] - m) * rs * gg.y + bb.y));
    hv.z = f2bf(leaky((acc2[r][2] - m) * rs * gg.z + bb.z));
    hv.w = f2bf(leaky((acc2[r][3] - m) * rs * gg.w + bb.w));
    *(ushort4*)&H1[(size_t)row * HD + cx*4] = hv;
  }
}

// ---------------- fused GIN layer 2: gather(H1) -> relu(.@w1+b1) -> (.@w2+b2) -> leaky -> atomicMax pool ----------------
__global__ __launch_bounds__(256) void k_layer2(const unsigned short* __restrict__ H1,
                                                const int* __restrict__ rowptr,
                                                const int* __restrict__ deg,
                                                const int* __restrict__ col,
                                                const int* __restrict__ batch,
                                                const float* __restrict__ w1,   // 256x256
                                                const float* __restrict__ b1,
                                                const float* __restrict__ w2,   // 256x256
                                                const float* __restrict__ b2,
                                                unsigned* __restrict__ Gk){
  __shared__ float zS[32 * HD];   // 32KB
  __shared__ float tS[32 * HD];   // 32KB
  const int tid = threadIdx.x;
  const int row0 = blockIdx.x * 32;
  const int lane = tid & 63;
  const int wv = tid >> 6;

  // gather z = h_i + sum h_j ; lane owns 4 cols (bf16x4 = 8B loads)
  const ushort4* h4 = (const ushort4*)H1;
  for (int rr = 0; rr < 8; ++rr){
    const int r = wv * 8 + rr;
    const int row = row0 + r;
    ushort4 a = h4[(size_t)row * 64 + lane];
    float4 f;
    f.x = bf2f(a.x); f.y = bf2f(a.y); f.z = bf2f(a.z); f.w = bf2f(a.w);
    const int p = rowptr[row], cnt = deg[row];
    for (int q = 0; q < cnt; ++q){
      const int j = col[p + q];
      ushort4 b = h4[(size_t)j * 64 + lane];
      f.x += bf2f(b.x); f.y += bf2f(b.y); f.z += bf2f(b.z); f.w += bf2f(b.w);
    }
    *(float4*)&zS[r * HD + lane * 4] = f;
  }
  __syncthreads();

  const int cx = lane;
  const int rg = wv;

  // GEMM-A: t = relu(z @ w1 + b1)
  float acc[8][4];
  {
    float4 b = *(const float4*)&b1[cx * 4];
    #pragma unroll
    for (int r = 0; r < 8; ++r){ acc[r][0]=b.x; acc[r][1]=b.y; acc[r][2]=b.z; acc[r][3]=b.w; }
  }
  {
    const float4* zS4 = (const float4*)zS;
    for (int k = 0; k < HD; k += 4){
      float4 w0 = *(const float4*)&w1[(size_t)(k+0)*HD + cx*4];
      float4 wA = *(const float4*)&w1[(size_t)(k+1)*HD + cx*4];
      float4 wB = *(const float4*)&w1[(size_t)(k+2)*HD + cx*4];
      float4 wC = *(const float4*)&w1[(size_t)(k+3)*HD + cx*4];
      #pragma unroll
      for (int r = 0; r < 8; ++r){
        float4 a = zS4[(rg*8 + r) * (HD/4) + (k >> 2)];
        acc[r][0] += a.x*w0.x + a.y*wA.x + a.z*wB.x + a.w*wC.x;
        acc[r][1] += a.x*w0.y + a.y*wA.y + a.z*wB.y + a.w*wC.y;
        acc[r][2] += a.x*w0.z + a.y*wA.z + a.z*wB.z + a.w*wC.z;
        acc[r][3] += a.x*w0.w + a.y*wA.w + a.z*wB.w + a.w*wC.w;
      }
    }
  }
  #pragma unroll
  for (int r = 0; r < 8; ++r){
    float4 o;
    o.x = fmaxf(acc[r][0], 0.f); o.y = fmaxf(acc[r][1], 0.f);
    o.z = fmaxf(acc[r][2], 0.f); o.w = fmaxf(acc[r][3], 0.f);
    *(float4*)&tS[(rg*8 + r) * HD + cx*4] = o;
  }
  __syncthreads();

  // GEMM-B: h = leaky(t @ w2 + b2) -> atomicMax pool by graph
  float acc2[8][4];
  {
    float4 b = *(const float4*)&b2[cx * 4];
    #pragma unroll
    for (int r = 0; r < 8; ++r){ acc2[r][0]=b.x; acc2[r][1]=b.y; acc2[r][2]=b.z; acc2[r][3]=b.w; }
  }
  {
    const float4* tS4 = (const float4*)tS;
    for (int k = 0; k < HD; k += 4){
      float4 w0 = *(const float4*)&w2[(size_t)(k+0)*HD + cx*4];
      float4 wA = *(const float4*)&w2[(size_t)(k+1)*HD + cx*4];
      float4 wB = *(const float4*)&w2[(size_t)(k+2)*HD + cx*4];
      float4 wC = *(const float4*)&w2[(size_t)(k+3)*HD + cx*4];
      #pragma unroll
      for (int r = 0; r < 8; ++r){
        float4 a = tS4[(rg*8 + r) * (HD/4) + (k >> 2)];
        acc2[r][0] += a.x*w0.x + a.y*wA.x + a.z*wB.x + a.w*wC.x;
        acc2[r][1] += a.x*w0.y + a.y*wA.y + a.z*wB.y + a.w*wC.y;
        acc2[r][2] += a.x*w0.z + a.y*wA.z + a.z*wB.z + a.w*wC.z;
        acc2[r][3] += a.x*w0.w + a.y*wA.w + a.z*wB.w + a.w*wC.w;
      }
    }
  }
  #pragma unroll
  for (int r = 0; r < 8; ++r){
    const int row = row0 + rg*8 + r;
    const int g = batch[row];
    unsigned* gk = Gk + (size_t)g * HD + cx*4;
    atomicMax(gk + 0, fkey(leaky(acc2[r][0])));
    atomicMax(gk + 1, fkey(leaky(acc2[r][1])));
    atomicMax(gk + 2, fkey(leaky(acc2[r][2])));
    atomicMax(gk + 3, fkey(leaky(acc2[r][3])));
  }
}

// ---------------- head: (g @ W1 + b1) -> LN(768) -> leaky -> @ W2 + b2 -> softmax(2) ----------------
__global__ __launch_bounds__(256) void head_kernel(const unsigned* __restrict__ Gk,
                                                   const float* __restrict__ w1,  // 256 x 768
                                                   const float* __restrict__ b1,
                                                   const float* __restrict__ lng,
                                                   const float* __restrict__ lnb,
                                                   const float* __restrict__ w2,  // 768 x 2
                                                   const float* __restrict__ b2,
                                                   float* __restrict__ out){
  __shared__ float gs[4][256];
  __shared__ float redA[4][4], redB[4][4];
  const int tid = threadIdx.x;
  const int g0 = blockIdx.x * 4;
  #pragma unroll
  for (int q = 0; q < 4; ++q) gs[q][tid] = fdec(Gk[(size_t)(g0 + q) * 256 + tid]);
  __syncthreads();

  float z[4][3];
  #pragma unroll
  for (int j = 0; j < 3; ++j){
    const int c = tid + j * 256;
    float a0 = b1[c], a1 = a0, a2 = a0, a3 = a0;
    #pragma unroll 8
    for (int k = 0; k < 256; ++k){
      float w = w1[(size_t)k * 768 + c];
      a0 += gs[0][k] * w; a1 += gs[1][k] * w; a2 += gs[2][k] * w; a3 += gs[3][k] * w;
    }
    z[0][j] = a0; z[1][j] = a1; z[2][j] = a2; z[3][j] = a3;
  }

  const int lane = tid & 63, wv = tid >> 6;
  float mean[4], rs[4];
  {
    float s1[4], s2[4];
    #pragma unroll
    for (int q = 0; q < 4; ++q){
      s1[q] = z[q][0] + z[q][1] + z[q][2];
      s2[q] = z[q][0]*z[q][0] + z[q][1]*z[q][1] + z[q][2]*z[q][2];
    }
    #pragma unroll
    for (int off = 32; off >= 1; off >>= 1){
      #pragma unroll
      for (int q = 0; q < 4; ++q){ s1[q] += __shfl_xor(s1[q], off); s2[q] += __shfl_xor(s2[q], off); }
    }
    if (lane == 0){
      #pragma unroll
      for (int q = 0; q < 4; ++q){ redA[q][wv] = s1[q]; redB[q][wv] = s2[q]; }
    }
    __syncthreads();
    #pragma unroll
    for (int q = 0; q < 4; ++q){
      float t1 = redA[q][0] + redA[q][1] + redA[q][2] + redA[q][3];
      float t2 = redB[q][0] + redB[q][1] + redB[q][2] + redB[q][3];
      float m = t1 * (1.f / 768.f);
      float v = t2 * (1.f / 768.f) - m * m;
      mean[q] = m; rs[q] = rsqrtf(v + LN_EPS);
    }
  }
  __syncthreads();

  float p0[4] = {0,0,0,0}, p1[4] = {0,0,0,0};
  #pragma unroll
  for (int j = 0; j < 3; ++j){
    const int c = tid + j * 256;
    float gcol = lng[c], bcol = lnb[c];
    float wa = w2[2 * c], wb = w2[2 * c + 1];
    #pragma unroll
    for (int q = 0; q < 4; ++q){
      float zz = leaky((z[q][j] - mean[q]) * rs[q] * gcol + bcol);
      p0[q] += zz * wa; p1[q] += zz * wb;
    }
  }
  #pragma unroll
  for (int off = 32; off >= 1; off >>= 1){
    #pragma unroll
    for (int q = 0; q < 4; ++q){ p0[q] += __shfl_xor(p0[q], off); p1[q] += __shfl_xor(p1[q], off); }
  }
  if (lane == 0){
    #pragma unroll
    for (int q = 0; q < 4; ++q){ redA[q][wv] = p0[q]; redB[q][wv] = p1[q]; }
  }
  __syncthreads();
  if (tid < 4){
    int q = tid;
    float l0 = redA[q][0] + redA[q][1] + redA[q][2] + redA[q][3] + b2[0];
    float l1 = redB[q][0] + redB[q][1] + redB[q][2] + redB[q][3] + b2[1];
    float mm = fmaxf(l0, l1);
    float e0 = expf(l0 - mm), e1 = expf(l1 - mm);
    float inv = 1.f / (e0 + e1);
    out[(size_t)(g0 + q) * 2 + 0] = e0 * inv;
    out[(size_t)(g0 + q) * 2 + 1] = e1 * inv;
  }
}

extern "C" void kernel_launch(void* const* d_in, const int* in_sizes, int n_in,
                              void* d_out, int out_size, void* d_ws, size_t ws_size,
                              hipStream_t stream){
  const float* x     = (const float*)d_in[0];
  const int*   ei    = (const int*)  d_in[1];
  const int*   batch = (const int*)  d_in[2];
  const float* g1w1  = (const float*)d_in[3];
  const float* g1b1  = (const float*)d_in[4];
  const float* g1w2  = (const float*)d_in[5];
  const float* g1b2  = (const float*)d_in[6];
  const float* g2w1  = (const float*)d_in[7];
  const float* g2b1  = (const float*)d_in[8];
  const float* g2w2  = (const float*)d_in[9];
  const float* g2b2  = (const float*)d_in[10];
  const float* lng   = (const float*)d_in[11];
  const float* lnb   = (const float*)d_in[12];
  const float* s2w1  = (const float*)d_in[13];
  const float* s2b1  = (const float*)d_in[14];
  const float* s2lng = (const float*)d_in[15];
  const float* s2lnb = (const float*)d_in[16];
  const float* s2w2  = (const float*)d_in[17];
  const float* s2b2  = (const float*)d_in[18];
  float* out = (float*)d_out;

  // compact workspace: 111,394,304 bytes total
  char* ws = (char*)d_ws;
  int*            rowptr = (int*)     (ws + 0);          //   800,000 B
  int*            cur    = (int*)     (ws + 800000);     //   800,000 B (deg counter / fill cursor / deg)
  int*            col    = (int*)     (ws + 1600000);    // 3,200,000 B
  unsigned*       Gk     = (unsigned*)(ws + 4800000);    // 4,194,304 B
  unsigned short* H1     = (unsigned short*)(ws + 8994304); // 102,400,000 B

  k_init <<<NG * HD / 256, 256, 0, stream>>>(cur, Gk);
  k_count<<<NE / 256,      256, 0, stream>>>(ei, cur);
  k_scan <<<1,            1024, 0, stream>>>(cur, rowptr);
  k_fill <<<NE / 256,      256, 0, stream>>>(ei, rowptr, cur, col);
  k_layer1<<<NN / 32, 256, 0, stream>>>(x, rowptr, cur, col,
                                        g1w1, g1b1, g1w2, g1b2, lng, lnb, H1);
  k_layer2<<<NN / 32, 256, 0, stream>>>(H1, rowptr, cur, col, batch,
                                        g2w1, g2b1, g2w2, g2b2, Gk);
  head_kernel<<<NG / 4, 256, 0, stream>>>(Gk, s2w1, s2b1, s2lng, s2lnb, s2w2, s2b2, out);
}

// Round 3
// 1540.887 us; speedup vs baseline: 1.6189x; 1.6189x over previous
//
#include <hip/hip_runtime.h>

#define NN 200000
#define NE 800000
#define NG 4096
#define AD 128
#define HD 256
#define LN_EPS 1e-5f

typedef __attribute__((ext_vector_type(8))) short     bf16x8;
typedef __attribute__((ext_vector_type(8))) unsigned short us8;
typedef __attribute__((ext_vector_type(4))) unsigned short us4;
typedef __attribute__((ext_vector_type(4))) float     f32x4;

__device__ __forceinline__ float leaky(float v){ return v > 0.f ? v : 0.2f*v; }

__device__ __forceinline__ unsigned short f2bf(float f){
  unsigned u = __float_as_uint(f);
  return (unsigned short)((u + 0x7FFFu + ((u >> 16) & 1u)) >> 16);
}
__device__ __forceinline__ float bf2f(unsigned short h){ return __uint_as_float(((unsigned)h) << 16); }

__device__ __forceinline__ unsigned fkey(float f){
  unsigned u = __float_as_uint(f);
  return (u & 0x80000000u) ? ~u : (u | 0x80000000u);
}
__device__ __forceinline__ float fdec(unsigned k){
  return (k & 0x80000000u) ? __uint_as_float(k & 0x7FFFFFFFu) : __uint_as_float(~k);
}

// ---------------- CSR build ----------------
__global__ __launch_bounds__(256) void k_zero(int* __restrict__ cur){
  int i = blockIdx.x * 256 + threadIdx.x;
  if (i < NN) cur[i] = 0;
}

__global__ __launch_bounds__(256) void k_count(const int* __restrict__ ei, int* __restrict__ cur){
  int e = blockIdx.x * 256 + threadIdx.x;
  atomicAdd(&cur[ei[NE + e]], 1);
}

__global__ __launch_bounds__(1024) void k_scan(int* __restrict__ cur, int* __restrict__ rowptr){
  __shared__ int sd[1024];
  const int t = threadIdx.x;
  const int lo = t * 196;
  const int hi = min(lo + 196, NN);
  int s = 0;
  for (int i = lo; i < hi; ++i) s += cur[i];
  sd[t] = s; __syncthreads();
  const int own = s;
  for (int off = 1; off < 1024; off <<= 1){
    int v = (t >= off) ? sd[t - off] : 0;
    __syncthreads();
    sd[t] += v;
    __syncthreads();
  }
  int prefix = sd[t] - own;
  for (int i = lo; i < hi; ++i){
    int v = cur[i];
    rowptr[i] = prefix;
    prefix += v;
    cur[i] = 0;
  }
  if (t == 1023) rowptr[NN] = prefix;   // == NE
}

__global__ __launch_bounds__(256) void k_fill(const int* __restrict__ ei,
                                              const int* __restrict__ rowptr,
                                              int* __restrict__ cur,
                                              int* __restrict__ col){
  int e = blockIdx.x * 256 + threadIdx.x;
  int s = ei[e], d = ei[NE + e];
  int pos = atomicAdd(&cur[d], 1);
  col[rowptr[d] + pos] = s;
}

// Gk init (runs AFTER k_fill: Gk aliases the cur buffer)
__global__ __launch_bounds__(256) void k_initG(unsigned* __restrict__ Gk){
  int i = blockIdx.x * 256 + threadIdx.x;   // grid = NG*HD/256
  Gk[i] = 0x00800000u;                      // fkey(-FLT_MAX)
}

// weights: f32 [K][256] -> bf16 transposed [256][K]
__global__ __launch_bounds__(256) void k_wprep(const float* __restrict__ src,
                                               unsigned short* __restrict__ dst, int K){
  int k = blockIdx.x, n = threadIdx.x;
  dst[(size_t)n * K + k] = f2bf(src[(size_t)k * 256 + n]);
}

// ---------------- fused GIN layer 1 (MFMA): gather(x)->relu(z@w1+b1)->LN(.@w2+b2)->leaky->bf16 H1 ----------------
__global__ __launch_bounds__(256) void k_layer1(const float* __restrict__ x,
                                                const int* __restrict__ rowptr,
                                                const int* __restrict__ col,
                                                const unsigned short* __restrict__ W1T,  // [256][128] bf16
                                                const float* __restrict__ b1,
                                                const unsigned short* __restrict__ W2T,  // [256][256] bf16
                                                const float* __restrict__ b2,
                                                const float* __restrict__ lng,
                                                const float* __restrict__ lnb,
                                                unsigned short* __restrict__ H1){
  __shared__ alignas(16) char zS[32 * AD * 2];   // 8KB, row stride 256B, XOR-swizzled
  __shared__ alignas(16) char tS[32 * HD * 2];   // 16KB, row stride 512B, XOR-swizzled
  __shared__ float2 redS[32][4];
  const int tid = threadIdx.x;
  const int l = tid & 63, wv = tid >> 6;
  const int cl = l & 15, kg = l >> 4;
  const int row0 = blockIdx.x * 32;

  // ---- gather z = x_i + sum_j x_j  (2 rows/wave/pass, lane owns 4 f32 cols) ----
  const float4* x4 = (const float4*)x;          // row stride 32 float4
  for (int pass = 0; pass < 4; ++pass){
    const int r = wv * 8 + pass * 2 + (l >> 5);
    const int row = row0 + r;
    const int half = l & 31;
    float4 a = x4[(size_t)row * 32 + half];
    const int p = rowptr[row], pe = rowptr[row + 1];
    for (int q = p; q < pe; ++q){
      const int j = col[q];
      float4 b = x4[(size_t)j * 32 + half];
      a.x += b.x; a.y += b.y; a.z += b.z; a.w += b.w;
    }
    us4 o; o[0] = f2bf(a.x); o[1] = f2bf(a.y); o[2] = f2bf(a.z); o[3] = f2bf(a.w);
    const int byteo = r * 256 + ((half * 8) ^ ((r & 7) << 4));
    *(us4*)&zS[byteo] = o;
  }
  __syncthreads();

  // ---- GEMM-A: t = relu(z @ w1 + b1), K=128, wave owns 32x64 col-strip ----
  f32x4 acc[2][4];
  #pragma unroll
  for (int nt = 0; nt < 4; ++nt){
    float bv = b1[wv * 64 + nt * 16 + cl];
    acc[0][nt] = (f32x4){bv, bv, bv, bv};
    acc[1][nt] = (f32x4){bv, bv, bv, bv};
  }
  #pragma unroll
  for (int ks = 0; ks < 4; ++ks){
    const int kb = (ks * 32 + kg * 8) * 2;
    bf16x8 a0 = *(const bf16x8*)&zS[(cl)      * 256 + (kb ^ ((cl & 7) << 4))];
    bf16x8 a1 = *(const bf16x8*)&zS[(16 + cl) * 256 + (kb ^ ((cl & 7) << 4))];
    #pragma unroll
    for (int nt = 0; nt < 4; ++nt){
      bf16x8 b = *(const bf16x8*)(W1T + (size_t)(wv * 64 + nt * 16 + cl) * AD + ks * 32 + kg * 8);
      acc[0][nt] = __builtin_amdgcn_mfma_f32_16x16x32_bf16(a0, b, acc[0][nt], 0, 0, 0);
      acc[1][nt] = __builtin_amdgcn_mfma_f32_16x16x32_bf16(a1, b, acc[1][nt], 0, 0, 0);
    }
  }
  #pragma unroll
  for (int mt = 0; mt < 2; ++mt)
    #pragma unroll
    for (int nt = 0; nt < 4; ++nt)
      #pragma unroll
      for (int rg = 0; rg < 4; ++rg){
        float v = fmaxf(acc[mt][nt][rg], 0.f);
        int row = mt * 16 + kg * 4 + rg;
        int cc = wv * 64 + nt * 16 + cl;
        *(unsigned short*)&tS[row * 512 + ((cc * 2) ^ ((row & 7) << 4))] = f2bf(v);
      }
  __syncthreads();

  // ---- GEMM-B: h = t @ w2 + b2, K=256 ----
  #pragma unroll
  for (int nt = 0; nt < 4; ++nt){
    float bv = b2[wv * 64 + nt * 16 + cl];
    acc[0][nt] = (f32x4){bv, bv, bv, bv};
    acc[1][nt] = (f32x4){bv, bv, bv, bv};
  }
  #pragma unroll
  for (int ks = 0; ks < 8; ++ks){
    const int kb = (ks * 32 + kg * 8) * 2;
    bf16x8 a0 = *(const bf16x8*)&tS[(cl)      * 512 + (kb ^ ((cl & 7) << 4))];
    bf16x8 a1 = *(const bf16x8*)&tS[(16 + cl) * 512 + (kb ^ ((cl & 7) << 4))];
    #pragma unroll
    for (int nt = 0; nt < 4; ++nt){
      bf16x8 b = *(const bf16x8*)(W2T + (size_t)(wv * 64 + nt * 16 + cl) * HD + ks * 32 + kg * 8);
      acc[0][nt] = __builtin_amdgcn_mfma_f32_16x16x32_bf16(a0, b, acc[0][nt], 0, 0, 0);
      acc[1][nt] = __builtin_amdgcn_mfma_f32_16x16x32_bf16(a1, b, acc[1][nt], 0, 0, 0);
    }
  }

  // ---- LN(256) + leaky + bf16 store; rows span 4 waves -> LDS reduce ----
  float s1[2][4], s2[2][4];
  #pragma unroll
  for (int mt = 0; mt < 2; ++mt)
    #pragma unroll
    for (int rg = 0; rg < 4; ++rg){
      float a = acc[mt][0][rg] + acc[mt][1][rg] + acc[mt][2][rg] + acc[mt][3][rg];
      float b = acc[mt][0][rg]*acc[mt][0][rg] + acc[mt][1][rg]*acc[mt][1][rg]
              + acc[mt][2][rg]*acc[mt][2][rg] + acc[mt][3][rg]*acc[mt][3][rg];
      #pragma unroll
      for (int off = 1; off <= 8; off <<= 1){ a += __shfl_xor(a, off); b += __shfl_xor(b, off); }
      s1[mt][rg] = a; s2[mt][rg] = b;
    }
  if (cl == 0){
    #pragma unroll
    for (int mt = 0; mt < 2; ++mt)
      #pragma unroll
      for (int rg = 0; rg < 4; ++rg)
        redS[mt * 16 + kg * 4 + rg][wv] = make_float2(s1[mt][rg], s2[mt][rg]);
  }
  __syncthreads();
  #pragma unroll
  for (int mt = 0; mt < 2; ++mt)
    #pragma unroll
    for (int rg = 0; rg < 4; ++rg){
      int row = mt * 16 + kg * 4 + rg;
      float t1 = redS[row][0].x + redS[row][1].x + redS[row][2].x + redS[row][3].x;
      float t2 = redS[row][0].y + redS[row][1].y + redS[row][2].y + redS[row][3].y;
      float m  = t1 * (1.f / HD);
      float vr = t2 * (1.f / HD) - m * m;
      float rs = rsqrtf(vr + LN_EPS);
      #pragma unroll
      for (int nt = 0; nt < 4; ++nt){
        int cc = wv * 64 + nt * 16 + cl;
        float v = (acc[mt][nt][rg] - m) * rs * lng[cc] + lnb[cc];
        H1[(size_t)(row0 + row) * HD + cc] = f2bf(leaky(v));
      }
    }
}

// ---------------- fused GIN layer 2 (MFMA): gather(H1)->relu(z@w1+b1)->(.@w2+b2)->leaky->atomicMax pool ----------------
__global__ __launch_bounds__(256) void k_layer2(const unsigned short* __restrict__ H1,
                                                const int* __restrict__ rowptr,
                                                const int* __restrict__ col,
                                                const int* __restrict__ batch,
                                                const unsigned short* __restrict__ W1T,  // [256][256]
                                                const float* __restrict__ b1,
                                                const unsigned short* __restrict__ W2T,  // [256][256]
                                                const float* __restrict__ b2,
                                                unsigned* __restrict__ Gk){
  __shared__ alignas(16) char zS[32 * HD * 2];   // 16KB, row stride 512B, swizzled
  __shared__ alignas(16) char tS[32 * HD * 2];   // 16KB
  const int tid = threadIdx.x;
  const int l = tid & 63, wv = tid >> 6;
  const int cl = l & 15, kg = l >> 4;
  const int row0 = blockIdx.x * 32;

  // ---- gather z = h_i + sum_j h_j  (2 rows/wave/pass, lane owns 8 bf16 cols) ----
  for (int pass = 0; pass < 4; ++pass){
    const int r = wv * 8 + pass * 2 + (l >> 5);
    const int row = row0 + r;
    const int half = l & 31;
    us8 a = *(const us8*)(H1 + (size_t)row * HD + half * 8);
    float f[8];
    #pragma unroll
    for (int j = 0; j < 8; ++j) f[j] = bf2f(a[j]);
    const int p = rowptr[row], pe = rowptr[row + 1];
    for (int q = p; q < pe; ++q){
      const int jn = col[q];
      us8 b = *(const us8*)(H1 + (size_t)jn * HD + half * 8);
      #pragma unroll
      for (int j = 0; j < 8; ++j) f[j] += bf2f(b[j]);
    }
    us8 o;
    #pragma unroll
    for (int j = 0; j < 8; ++j) o[j] = f2bf(f[j]);
    const int byteo = r * 512 + ((half * 16) ^ ((r & 7) << 4));
    *(us8*)&zS[byteo] = o;
  }
  __syncthreads();

  // ---- GEMM-A: t = relu(z @ w1 + b1), K=256 ----
  f32x4 acc[2][4];
  #pragma unroll
  for (int nt = 0; nt < 4; ++nt){
    float bv = b1[wv * 64 + nt * 16 + cl];
    acc[0][nt] = (f32x4){bv, bv, bv, bv};
    acc[1][nt] = (f32x4){bv, bv, bv, bv};
  }
  #pragma unroll
  for (int ks = 0; ks < 8; ++ks){
    const int kb = (ks * 32 + kg * 8) * 2;
    bf16x8 a0 = *(const bf16x8*)&zS[(cl)      * 512 + (kb ^ ((cl & 7) << 4))];
    bf16x8 a1 = *(const bf16x8*)&zS[(16 + cl) * 512 + (kb ^ ((cl & 7) << 4))];
    #pragma unroll
    for (int nt = 0; nt < 4; ++nt){
      bf16x8 b = *(const bf16x8*)(W1T + (size_t)(wv * 64 + nt * 16 + cl) * HD + ks * 32 + kg * 8);
      acc[0][nt] = __builtin_amdgcn_mfma_f32_16x16x32_bf16(a0, b, acc[0][nt], 0, 0, 0);
      acc[1][nt] = __builtin_amdgcn_mfma_f32_16x16x32_bf16(a1, b, acc[1][nt], 0, 0, 0);
    }
  }
  #pragma unroll
  for (int mt = 0; mt < 2; ++mt)
    #pragma unroll
    for (int nt = 0; nt < 4; ++nt)
      #pragma unroll
      for (int rg = 0; rg < 4; ++rg){
        float v = fmaxf(acc[mt][nt][rg], 0.f);
        int row = mt * 16 + kg * 4 + rg;
        int cc = wv * 64 + nt * 16 + cl;
        *(unsigned short*)&tS[row * 512 + ((cc * 2) ^ ((row & 7) << 4))] = f2bf(v);
      }
  __syncthreads();

  // ---- GEMM-B: h = t @ w2 + b2, K=256 ----
  #pragma unroll
  for (int nt = 0; nt < 4; ++nt){
    float bv = b2[wv * 64 + nt * 16 + cl];
    acc[0][nt] = (f32x4){bv, bv, bv, bv};
    acc[1][nt] = (f32x4){bv, bv, bv, bv};
  }
  #pragma unroll
  for (int ks = 0; ks < 8; ++ks){
    const int kb = (ks * 32 + kg * 8) * 2;
    bf16x8 a0 = *(const bf16x8*)&tS[(cl)      * 512 + (kb ^ ((cl & 7) << 4))];
    bf16x8 a1 = *(const bf16x8*)&tS[(16 + cl) * 512 + (kb ^ ((cl & 7) << 4))];
    #pragma unroll
    for (int nt = 0; nt < 4; ++nt){
      bf16x8 b = *(const bf16x8*)(W2T + (size_t)(wv * 64 + nt * 16 + cl) * HD + ks * 32 + kg * 8);
      acc[0][nt] = __builtin_amdgcn_mfma_f32_16x16x32_bf16(a0, b, acc[0][nt], 0, 0, 0);
      acc[1][nt] = __builtin_amdgcn_mfma_f32_16x16x32_bf16(a1, b, acc[1][nt], 0, 0, 0);
    }
  }

  // ---- leaky + atomicMax pool ----
  #pragma unroll
  for (int mt = 0; mt < 2; ++mt)
    #pragma unroll
    for (int rg = 0; rg < 4; ++rg){
      int row = row0 + mt * 16 + kg * 4 + rg;
      int g = batch[row];
      unsigned* gp = Gk + (size_t)g * HD;
      #pragma unroll
      for (int nt = 0; nt < 4; ++nt){
        int cc = wv * 64 + nt * 16 + cl;
        atomicMax(&gp[cc], fkey(leaky(acc[mt][nt][rg])));
      }
    }
}

// ---------------- head: (g @ W1 + b1) -> LN(768) -> leaky -> @ W2 + b2 -> softmax(2) ----------------
__global__ __launch_bounds__(256) void head_kernel(const unsigned* __restrict__ Gk,
                                                   const float* __restrict__ w1,
                                                   const float* __restrict__ b1,
                                                   const float* __restrict__ lng,
                                                   const float* __restrict__ lnb,
                                                   const float* __restrict__ w2,
                                                   const float* __restrict__ b2,
                                                   float* __restrict__ out){
  __shared__ float gs[4][256];
  __shared__ float redA[4][4], redB[4][4];
  const int tid = threadIdx.x;
  const int g0 = blockIdx.x * 4;
  #pragma unroll
  for (int q = 0; q < 4; ++q) gs[q][tid] = fdec(Gk[(size_t)(g0 + q) * 256 + tid]);
  __syncthreads();

  float z[4][3];
  #pragma unroll
  for (int j = 0; j < 3; ++j){
    const int c = tid + j * 256;
    float a0 = b1[c], a1 = a0, a2 = a0, a3 = a0;
    #pragma unroll 8
    for (int k = 0; k < 256; ++k){
      float w = w1[(size_t)k * 768 + c];
      a0 += gs[0][k] * w; a1 += gs[1][k] * w; a2 += gs[2][k] * w; a3 += gs[3][k] * w;
    }
    z[0][j] = a0; z[1][j] = a1; z[2][j] = a2; z[3][j] = a3;
  }

  const int lane = tid & 63, wv = tid >> 6;
  float mean[4], rs[4];
  {
    float s1[4], s2[4];
    #pragma unroll
    for (int q = 0; q < 4; ++q){
      s1[q] = z[q][0] + z[q][1] + z[q][2];
      s2[q] = z[q][0]*z[q][0] + z[q][1]*z[q][1] + z[q][2]*z[q][2];
    }
    #pragma unroll
    for (int off = 32; off >= 1; off >>= 1){
      #pragma unroll
      for (int q = 0; q < 4; ++q){ s1[q] += __shfl_xor(s1[q], off); s2[q] += __shfl_xor(s2[q], off); }
    }
    if (lane == 0){
      #pragma unroll
      for (int q = 0; q < 4; ++q){ redA[q][wv] = s1[q]; redB[q][wv] = s2[q]; }
    }
    __syncthreads();
    #pragma unroll
    for (int q = 0; q < 4; ++q){
      float t1 = redA[q][0] + redA[q][1] + redA[q][2] + redA[q][3];
      float t2 = redB[q][0] + redB[q][1] + redB[q][2] + redB[q][3];
      float m = t1 * (1.f / 768.f);
      float v = t2 * (1.f / 768.f) - m * m;
      mean[q] = m; rs[q] = rsqrtf(v + LN_EPS);
    }
  }
  __syncthreads();

  float p0[4] = {0,0,0,0}, p1[4] = {0,0,0,0};
  #pragma unroll
  for (int j = 0; j < 3; ++j){
    const int c = tid + j * 256;
    float gcol = lng[c], bcol = lnb[c];
    float wa = w2[2 * c], wb = w2[2 * c + 1];
    #pragma unroll
    for (int q = 0; q < 4; ++q){
      float zz = leaky((z[q][j] - mean[q]) * rs[q] * gcol + bcol);
      p0[q] += zz * wa; p1[q] += zz * wb;
    }
  }
  #pragma unroll
  for (int off = 32; off >= 1; off >>= 1){
    #pragma unroll
    for (int q = 0; q < 4; ++q){ p0[q] += __shfl_xor(p0[q], off); p1[q] += __shfl_xor(p1[q], off); }
  }
  if (lane == 0){
    #pragma unroll
    for (int q = 0; q < 4; ++q){ redA[q][wv] = p0[q]; redB[q][wv] = p1[q]; }
  }
  __syncthreads();
  if (tid < 4){
    int q = tid;
    float l0 = redA[q][0] + redA[q][1] + redA[q][2] + redA[q][3] + b2[0];
    float l1 = redB[q][0] + redB[q][1] + redB[q][2] + redB[q][3] + b2[1];
    float mm = fmaxf(l0, l1);
    float e0 = expf(l0 - mm), e1 = expf(l1 - mm);
    float inv = 1.f / (e0 + e1);
    out[(size_t)(g0 + q) * 2 + 0] = e0 * inv;
    out[(size_t)(g0 + q) * 2 + 1] = e1 * inv;
  }
}

extern "C" void kernel_launch(void* const* d_in, const int* in_sizes, int n_in,
                              void* d_out, int out_size, void* d_ws, size_t ws_size,
                              hipStream_t stream){
  const float* x     = (const float*)d_in[0];
  const int*   ei    = (const int*)  d_in[1];
  const int*   batch = (const int*)  d_in[2];
  const float* g1w1  = (const float*)d_in[3];
  const float* g1b1  = (const float*)d_in[4];
  const float* g1w2  = (const float*)d_in[5];
  const float* g1b2  = (const float*)d_in[6];
  const float* g2w1  = (const float*)d_in[7];
  const float* g2b1  = (const float*)d_in[8];
  const float* g2w2  = (const float*)d_in[9];
  const float* g2b2  = (const float*)d_in[10];
  const float* lng   = (const float*)d_in[11];
  const float* lnb   = (const float*)d_in[12];
  const float* s2w1  = (const float*)d_in[13];
  const float* s2b1  = (const float*)d_in[14];
  const float* s2lng = (const float*)d_in[15];
  const float* s2lnb = (const float*)d_in[16];
  const float* s2w2  = (const float*)d_in[17];
  const float* s2b2  = (const float*)d_in[18];
  float* out = (float*)d_out;

  // workspace: 111,053,088 B total (< 111.39 MB proven in round 2)
  char* ws = (char*)d_ws;
  int*            rowptr = (int*)(ws + 0);                    //   800,032 B (NN+1 ints, padded)
  int*            col    = (int*)(ws + 800032);               // 3,200,000 B
  unsigned*       Gk     = (unsigned*)(ws + 4000032);         // 4,194,304 B (aliases 'cur' during CSR build)
  int*            cur    = (int*)Gk;
  unsigned short* W1T1   = (unsigned short*)(ws + 8194336);   //    65,536 B
  unsigned short* W2T1   = (unsigned short*)(ws + 8259872);   //   131,072 B
  unsigned short* W1T2   = (unsigned short*)(ws + 8390944);   //   131,072 B
  unsigned short* W2T2   = (unsigned short*)(ws + 8522016);   //   131,072 B
  unsigned short* H1     = (unsigned short*)(ws + 8653088);   // 102,400,000 B

  k_zero <<<(NN + 255) / 256, 256, 0, stream>>>(cur);
  k_count<<<NE / 256,         256, 0, stream>>>(ei, cur);
  k_scan <<<1,               1024, 0, stream>>>(cur, rowptr);
  k_fill <<<NE / 256,         256, 0, stream>>>(ei, rowptr, cur, col);
  k_initG<<<NG * HD / 256,    256, 0, stream>>>(Gk);
  k_wprep<<<128, 256, 0, stream>>>(g1w1, W1T1, 128);
  k_wprep<<<256, 256, 0, stream>>>(g1w2, W2T1, 256);
  k_wprep<<<256, 256, 0, stream>>>(g2w1, W1T2, 256);
  k_wprep<<<256, 256, 0, stream>>>(g2w2, W2T2, 256);
  k_layer1<<<NN / 32, 256, 0, stream>>>(x, rowptr, col, W1T1, g1b1, W2T1, g1b2, lng, lnb, H1);
  k_layer2<<<NN / 32, 256, 0, stream>>>(H1, rowptr, col, batch, W1T2, g2b1, W2T2, g2b2, Gk);
  head_kernel<<<NG / 4, 256, 0, stream>>>(Gk, s2w1, s2b1, s2lng, s2lnb, s2w2, s2b2, out);
}

// Round 4
// 1489.252 us; speedup vs baseline: 1.6751x; 1.0347x over previous
//
#include <hip/hip_runtime.h>

#define NN 200000
#define NE 800000
#define NG 4096
#define AD 128
#define HD 256
#define LN_EPS 1e-5f

typedef __attribute__((ext_vector_type(8))) short     bf16x8;
typedef __attribute__((ext_vector_type(8))) unsigned short us8;
typedef __attribute__((ext_vector_type(4))) unsigned short us4;
typedef __attribute__((ext_vector_type(4))) float     f32x4;

__device__ __forceinline__ float leaky(float v){ return v > 0.f ? v : 0.2f*v; }

__device__ __forceinline__ unsigned short f2bf(float f){
  unsigned u = __float_as_uint(f);
  return (unsigned short)((u + 0x7FFFu + ((u >> 16) & 1u)) >> 16);
}
__device__ __forceinline__ float bf2f(unsigned short h){ return __uint_as_float(((unsigned)h) << 16); }

__device__ __forceinline__ unsigned fkey(float f){
  unsigned u = __float_as_uint(f);
  return (u & 0x80000000u) ? ~u : (u | 0x80000000u);
}
__device__ __forceinline__ float fdec(unsigned k){
  return (k & 0x80000000u) ? __uint_as_float(k & 0x7FFFFFFFu) : __uint_as_float(~k);
}

// ---------------- CSR build ----------------
__global__ __launch_bounds__(256) void k_zero(int* __restrict__ cur){
  int i = blockIdx.x * 256 + threadIdx.x;
  if (i < NN) cur[i] = 0;
}

__global__ __launch_bounds__(256) void k_count(const int* __restrict__ ei, int* __restrict__ cur){
  int e = blockIdx.x * 256 + threadIdx.x;
  atomicAdd(&cur[ei[NE + e]], 1);
}

__global__ __launch_bounds__(1024) void k_scan(int* __restrict__ cur, int* __restrict__ rowptr){
  __shared__ int sd[1024];
  const int t = threadIdx.x;
  const int lo = t * 196;
  const int hi = min(lo + 196, NN);
  int s = 0;
  for (int i = lo; i < hi; ++i) s += cur[i];
  sd[t] = s; __syncthreads();
  const int own = s;
  for (int off = 1; off < 1024; off <<= 1){
    int v = (t >= off) ? sd[t - off] : 0;
    __syncthreads();
    sd[t] += v;
    __syncthreads();
  }
  int prefix = sd[t] - own;
  for (int i = lo; i < hi; ++i){
    int v = cur[i];
    rowptr[i] = prefix;
    prefix += v;
    cur[i] = 0;
  }
  if (t == 1023) rowptr[NN] = prefix;
}

__global__ __launch_bounds__(256) void k_fill(const int* __restrict__ ei,
                                              const int* __restrict__ rowptr,
                                              int* __restrict__ cur,
                                              int* __restrict__ col){
  int e = blockIdx.x * 256 + threadIdx.x;
  int s = ei[e], d = ei[NE + e];
  int pos = atomicAdd(&cur[d], 1);
  col[rowptr[d] + pos] = s;
}

__global__ __launch_bounds__(256) void k_initG(unsigned* __restrict__ Gk){
  int i = blockIdx.x * 256 + threadIdx.x;
  Gk[i] = 0x00800000u;                      // fkey(-FLT_MAX)
}

// weights: f32 [K][256] -> bf16 transposed [256][K]
__global__ __launch_bounds__(256) void k_wprep(const float* __restrict__ src,
                                               unsigned short* __restrict__ dst, int K){
  int k = blockIdx.x, n = threadIdx.x;
  dst[(size_t)n * K + k] = f2bf(src[(size_t)k * 256 + n]);
}

// ---------------- fused GIN layer 1 (MFMA, aliased LDS, pipelined gather) ----------------
__global__ __launch_bounds__(256) void k_layer1(const float* __restrict__ x,
                                                const int* __restrict__ rowptr,
                                                const int* __restrict__ col,
                                                const unsigned short* __restrict__ W1T,  // [256][128] bf16
                                                const float* __restrict__ b1,
                                                const unsigned short* __restrict__ W2T,  // [256][256] bf16
                                                const float* __restrict__ b2,
                                                const float* __restrict__ lng,
                                                const float* __restrict__ lnb,
                                                unsigned short* __restrict__ H1){
  __shared__ alignas(16) char sS[32 * 512];      // 16KB: zS (256B rows) then tS (512B rows)
  __shared__ float2 redS[32][4];
  const int tid = threadIdx.x;
  const int l = tid & 63, wv = tid >> 6;
  const int cl = l & 15, kg = l >> 4;
  const int row0 = blockIdx.x * 32;

  // ---- gather z = x_i + sum_j x_j  (2 rows/wave/pass; lane owns 16B; 4-deep pipelined) ----
  const float4* x4 = (const float4*)x;           // row stride 32 float4
  for (int pass = 0; pass < 4; ++pass){
    const int r = wv * 8 + pass * 2 + (l >> 5);
    const int row = row0 + r;
    const int half = l & 31;
    float4 a = x4[(size_t)row * 32 + half];
    const int p = rowptr[row], pe = rowptr[row + 1];
    int q = p;
    for (; q + 4 <= pe; q += 4){
      int j0 = col[q], j1 = col[q+1], j2 = col[q+2], j3 = col[q+3];
      float4 b0 = x4[(size_t)j0 * 32 + half];
      float4 b1v = x4[(size_t)j1 * 32 + half];
      float4 b2v = x4[(size_t)j2 * 32 + half];
      float4 b3 = x4[(size_t)j3 * 32 + half];
      a.x += (b0.x + b1v.x) + (b2v.x + b3.x);
      a.y += (b0.y + b1v.y) + (b2v.y + b3.y);
      a.z += (b0.z + b1v.z) + (b2v.z + b3.z);
      a.w += (b0.w + b1v.w) + (b2v.w + b3.w);
    }
    for (; q < pe; ++q){
      const int j = col[q];
      float4 b = x4[(size_t)j * 32 + half];
      a.x += b.x; a.y += b.y; a.z += b.z; a.w += b.w;
    }
    us4 o; o[0] = f2bf(a.x); o[1] = f2bf(a.y); o[2] = f2bf(a.z); o[3] = f2bf(a.w);
    const int byteo = r * 256 + ((half * 8) ^ ((r & 7) << 4));
    *(us4*)&sS[byteo] = o;
  }
  __syncthreads();

  // ---- GEMM-A: t = relu(z @ w1 + b1), K=128 ----
  f32x4 acc[2][4];
  #pragma unroll
  for (int nt = 0; nt < 4; ++nt){
    float bv = b1[wv * 64 + nt * 16 + cl];
    acc[0][nt] = (f32x4){bv, bv, bv, bv};
    acc[1][nt] = (f32x4){bv, bv, bv, bv};
  }
  #pragma unroll
  for (int ks = 0; ks < 4; ++ks){
    const int kb = (ks * 32 + kg * 8) * 2;
    bf16x8 a0 = *(const bf16x8*)&sS[(cl)      * 256 + (kb ^ ((cl & 7) << 4))];
    bf16x8 a1 = *(const bf16x8*)&sS[(16 + cl) * 256 + (kb ^ ((cl & 7) << 4))];
    #pragma unroll
    for (int nt = 0; nt < 4; ++nt){
      bf16x8 b = *(const bf16x8*)(W1T + (size_t)(wv * 64 + nt * 16 + cl) * AD + ks * 32 + kg * 8);
      acc[0][nt] = __builtin_amdgcn_mfma_f32_16x16x32_bf16(a0, b, acc[0][nt], 0, 0, 0);
      acc[1][nt] = __builtin_amdgcn_mfma_f32_16x16x32_bf16(a1, b, acc[1][nt], 0, 0, 0);
    }
  }
  __syncthreads();   // all waves done reading zS -> safe to overwrite with tS
  #pragma unroll
  for (int mt = 0; mt < 2; ++mt)
    #pragma unroll
    for (int nt = 0; nt < 4; ++nt)
      #pragma unroll
      for (int rg = 0; rg < 4; ++rg){
        float v = fmaxf(acc[mt][nt][rg], 0.f);
        int row = mt * 16 + kg * 4 + rg;
        int cc = wv * 64 + nt * 16 + cl;
        *(unsigned short*)&sS[row * 512 + ((cc * 2) ^ ((row & 7) << 4))] = f2bf(v);
      }
  __syncthreads();

  // ---- GEMM-B: h = t @ w2 + b2, K=256 ----
  #pragma unroll
  for (int nt = 0; nt < 4; ++nt){
    float bv = b2[wv * 64 + nt * 16 + cl];
    acc[0][nt] = (f32x4){bv, bv, bv, bv};
    acc[1][nt] = (f32x4){bv, bv, bv, bv};
  }
  #pragma unroll
  for (int ks = 0; ks < 8; ++ks){
    const int kb = (ks * 32 + kg * 8) * 2;
    bf16x8 a0 = *(const bf16x8*)&sS[(cl)      * 512 + (kb ^ ((cl & 7) << 4))];
    bf16x8 a1 = *(const bf16x8*)&sS[(16 + cl) * 512 + (kb ^ ((cl & 7) << 4))];
    #pragma unroll
    for (int nt = 0; nt < 4; ++nt){
      bf16x8 b = *(const bf16x8*)(W2T + (size_t)(wv * 64 + nt * 16 + cl) * HD + ks * 32 + kg * 8);
      acc[0][nt] = __builtin_amdgcn_mfma_f32_16x16x32_bf16(a0, b, acc[0][nt], 0, 0, 0);
      acc[1][nt] = __builtin_amdgcn_mfma_f32_16x16x32_bf16(a1, b, acc[1][nt], 0, 0, 0);
    }
  }

  // ---- LN(256) + leaky + bf16 store ----
  float s1[2][4], s2[2][4];
  #pragma unroll
  for (int mt = 0; mt < 2; ++mt)
    #pragma unroll
    for (int rg = 0; rg < 4; ++rg){
      float a = acc[mt][0][rg] + acc[mt][1][rg] + acc[mt][2][rg] + acc[mt][3][rg];
      float b = acc[mt][0][rg]*acc[mt][0][rg] + acc[mt][1][rg]*acc[mt][1][rg]
              + acc[mt][2][rg]*acc[mt][2][rg] + acc[mt][3][rg]*acc[mt][3][rg];
      #pragma unroll
      for (int off = 1; off <= 8; off <<= 1){ a += __shfl_xor(a, off); b += __shfl_xor(b, off); }
      s1[mt][rg] = a; s2[mt][rg] = b;
    }
  if (cl == 0){
    #pragma unroll
    for (int mt = 0; mt < 2; ++mt)
      #pragma unroll
      for (int rg = 0; rg < 4; ++rg)
        redS[mt * 16 + kg * 4 + rg][wv] = make_float2(s1[mt][rg], s2[mt][rg]);
  }
  __syncthreads();
  #pragma unroll
  for (int mt = 0; mt < 2; ++mt)
    #pragma unroll
    for (int rg = 0; rg < 4; ++rg){
      int row = mt * 16 + kg * 4 + rg;
      float t1 = redS[row][0].x + redS[row][1].x + redS[row][2].x + redS[row][3].x;
      float t2 = redS[row][0].y + redS[row][1].y + redS[row][2].y + redS[row][3].y;
      float m  = t1 * (1.f / HD);
      float vr = t2 * (1.f / HD) - m * m;
      float rs = rsqrtf(vr + LN_EPS);
      #pragma unroll
      for (int nt = 0; nt < 4; ++nt){
        int cc = wv * 64 + nt * 16 + cl;
        float v = (acc[mt][nt][rg] - m) * rs * lng[cc] + lnb[cc];
        H1[(size_t)(row0 + row) * HD + cc] = f2bf(leaky(v));
      }
    }
}

// ---------------- fused GIN layer 2 (MFMA, aliased LDS, pipelined gather) ----------------
__global__ __launch_bounds__(256) void k_layer2(const unsigned short* __restrict__ H1,
                                                const int* __restrict__ rowptr,
                                                const int* __restrict__ col,
                                                const int* __restrict__ batch,
                                                const unsigned short* __restrict__ W1T,  // [256][256]
                                                const float* __restrict__ b1,
                                                const unsigned short* __restrict__ W2T,  // [256][256]
                                                const float* __restrict__ b2,
                                                unsigned* __restrict__ Gk){
  __shared__ alignas(16) char sS[32 * 512];      // 16KB: zS then tS (both 512B rows)
  const int tid = threadIdx.x;
  const int l = tid & 63, wv = tid >> 6;
  const int cl = l & 15, kg = l >> 4;
  const int row0 = blockIdx.x * 32;

  // ---- gather z = h_i + sum_j h_j  (lane owns 8 bf16 cols; 4-deep pipelined) ----
  for (int pass = 0; pass < 4; ++pass){
    const int r = wv * 8 + pass * 2 + (l >> 5);
    const int row = row0 + r;
    const int half = l & 31;
    us8 a = *(const us8*)(H1 + (size_t)row * HD + half * 8);
    float f[8];
    #pragma unroll
    for (int j = 0; j < 8; ++j) f[j] = bf2f(a[j]);
    const int p = rowptr[row], pe = rowptr[row + 1];
    int q = p;
    for (; q + 4 <= pe; q += 4){
      int j0 = col[q], j1 = col[q+1], j2 = col[q+2], j3 = col[q+3];
      us8 b0 = *(const us8*)(H1 + (size_t)j0 * HD + half * 8);
      us8 b1v = *(const us8*)(H1 + (size_t)j1 * HD + half * 8);
      us8 b2v = *(const us8*)(H1 + (size_t)j2 * HD + half * 8);
      us8 b3 = *(const us8*)(H1 + (size_t)j3 * HD + half * 8);
      #pragma unroll
      for (int j = 0; j < 8; ++j)
        f[j] += (bf2f(b0[j]) + bf2f(b1v[j])) + (bf2f(b2v[j]) + bf2f(b3[j]));
    }
    for (; q < pe; ++q){
      const int jn = col[q];
      us8 b = *(const us8*)(H1 + (size_t)jn * HD + half * 8);
      #pragma unroll
      for (int j = 0; j < 8; ++j) f[j] += bf2f(b[j]);
    }
    us8 o;
    #pragma unroll
    for (int j = 0; j < 8; ++j) o[j] = f2bf(f[j]);
    const int byteo = r * 512 + ((half * 16) ^ ((r & 7) << 4));
    *(us8*)&sS[byteo] = o;
  }
  __syncthreads();

  // ---- GEMM-A: t = relu(z @ w1 + b1), K=256 ----
  f32x4 acc[2][4];
  #pragma unroll
  for (int nt = 0; nt < 4; ++nt){
    float bv = b1[wv * 64 + nt * 16 + cl];
    acc[0][nt] = (f32x4){bv, bv, bv, bv};
    acc[1][nt] = (f32x4){bv, bv, bv, bv};
  }
  #pragma unroll
  for (int ks = 0; ks < 8; ++ks){
    const int kb = (ks * 32 + kg * 8) * 2;
    bf16x8 a0 = *(const bf16x8*)&sS[(cl)      * 512 + (kb ^ ((cl & 7) << 4))];
    bf16x8 a1 = *(const bf16x8*)&sS[(16 + cl) * 512 + (kb ^ ((cl & 7) << 4))];
    #pragma unroll
    for (int nt = 0; nt < 4; ++nt){
      bf16x8 b = *(const bf16x8*)(W1T + (size_t)(wv * 64 + nt * 16 + cl) * HD + ks * 32 + kg * 8);
      acc[0][nt] = __builtin_amdgcn_mfma_f32_16x16x32_bf16(a0, b, acc[0][nt], 0, 0, 0);
      acc[1][nt] = __builtin_amdgcn_mfma_f32_16x16x32_bf16(a1, b, acc[1][nt], 0, 0, 0);
    }
  }
  __syncthreads();   // all waves done reading zS
  #pragma unroll
  for (int mt = 0; mt < 2; ++mt)
    #pragma unroll
    for (int nt = 0; nt < 4; ++nt)
      #pragma unroll
      for (int rg = 0; rg < 4; ++rg){
        float v = fmaxf(acc[mt][nt][rg], 0.f);
        int row = mt * 16 + kg * 4 + rg;
        int cc = wv * 64 + nt * 16 + cl;
        *(unsigned short*)&sS[row * 512 + ((cc * 2) ^ ((row & 7) << 4))] = f2bf(v);
      }
  __syncthreads();

  // ---- GEMM-B: h = t @ w2 + b2, K=256 ----
  #pragma unroll
  for (int nt = 0; nt < 4; ++nt){
    float bv = b2[wv * 64 + nt * 16 + cl];
    acc[0][nt] = (f32x4){bv, bv, bv, bv};
    acc[1][nt] = (f32x4){bv, bv, bv, bv};
  }
  #pragma unroll
  for (int ks = 0; ks < 8; ++ks){
    const int kb = (ks * 32 + kg * 8) * 2;
    bf16x8 a0 = *(const bf16x8*)&sS[(cl)      * 512 + (kb ^ ((cl & 7) << 4))];
    bf16x8 a1 = *(const bf16x8*)&sS[(16 + cl) * 512 + (kb ^ ((cl & 7) << 4))];
    #pragma unroll
    for (int nt = 0; nt < 4; ++nt){
      bf16x8 b = *(const bf16x8*)(W2T + (size_t)(wv * 64 + nt * 16 + cl) * HD + ks * 32 + kg * 8);
      acc[0][nt] = __builtin_amdgcn_mfma_f32_16x16x32_bf16(a0, b, acc[0][nt], 0, 0, 0);
      acc[1][nt] = __builtin_amdgcn_mfma_f32_16x16x32_bf16(a1, b, acc[1][nt], 0, 0, 0);
    }
  }

  // ---- leaky + atomicMax pool ----
  #pragma unroll
  for (int mt = 0; mt < 2; ++mt)
    #pragma unroll
    for (int rg = 0; rg < 4; ++rg){
      int row = row0 + mt * 16 + kg * 4 + rg;
      int g = batch[row];
      unsigned* gp = Gk + (size_t)g * HD;
      #pragma unroll
      for (int nt = 0; nt < 4; ++nt){
        int cc = wv * 64 + nt * 16 + cl;
        atomicMax(&gp[cc], fkey(leaky(acc[mt][nt][rg])));
      }
    }
}

// ---------------- head ----------------
__global__ __launch_bounds__(256) void head_kernel(const unsigned* __restrict__ Gk,
                                                   const float* __restrict__ w1,
                                                   const float* __restrict__ b1,
                                                   const float* __restrict__ lng,
                                                   const float* __restrict__ lnb,
                                                   const float* __restrict__ w2,
                                                   const float* __restrict__ b2,
                                                   float* __restrict__ out){
  __shared__ float gs[4][256];
  __shared__ float redA[4][4], redB[4][4];
  const int tid = threadIdx.x;
  const int g0 = blockIdx.x * 4;
  #pragma unroll
  for (int q = 0; q < 4; ++q) gs[q][tid] = fdec(Gk[(size_t)(g0 + q) * 256 + tid]);
  __syncthreads();

  float z[4][3];
  #pragma unroll
  for (int j = 0; j < 3; ++j){
    const int c = tid + j * 256;
    float a0 = b1[c], a1 = a0, a2 = a0, a3 = a0;
    #pragma unroll 8
    for (int k = 0; k < 256; ++k){
      float w = w1[(size_t)k * 768 + c];
      a0 += gs[0][k] * w; a1 += gs[1][k] * w; a2 += gs[2][k] * w; a3 += gs[3][k] * w;
    }
    z[0][j] = a0; z[1][j] = a1; z[2][j] = a2; z[3][j] = a3;
  }

  const int lane = tid & 63, wv = tid >> 6;
  float mean[4], rs[4];
  {
    float s1[4], s2[4];
    #pragma unroll
    for (int q = 0; q < 4; ++q){
      s1[q] = z[q][0] + z[q][1] + z[q][2];
      s2[q] = z[q][0]*z[q][0] + z[q][1]*z[q][1] + z[q][2]*z[q][2];
    }
    #pragma unroll
    for (int off = 32; off >= 1; off >>= 1){
      #pragma unroll
      for (int q = 0; q < 4; ++q){ s1[q] += __shfl_xor(s1[q], off); s2[q] += __shfl_xor(s2[q], off); }
    }
    if (lane == 0){
      #pragma unroll
      for (int q = 0; q < 4; ++q){ redA[q][wv] = s1[q]; redB[q][wv] = s2[q]; }
    }
    __syncthreads();
    #pragma unroll
    for (int q = 0; q < 4; ++q){
      float t1 = redA[q][0] + redA[q][1] + redA[q][2] + redA[q][3];
      float t2 = redB[q][0] + redB[q][1] + redB[q][2] + redB[q][3];
      float m = t1 * (1.f / 768.f);
      float v = t2 * (1.f / 768.f) - m * m;
      mean[q] = m; rs[q] = rsqrtf(v + LN_EPS);
    }
  }
  __syncthreads();

  float p0[4] = {0,0,0,0}, p1[4] = {0,0,0,0};
  #pragma unroll
  for (int j = 0; j < 3; ++j){
    const int c = tid + j * 256;
    float gcol = lng[c], bcol = lnb[c];
    float wa = w2[2 * c], wb = w2[2 * c + 1];
    #pragma unroll
    for (int q = 0; q < 4; ++q){
      float zz = leaky((z[q][j] - mean[q]) * rs[q] * gcol + bcol);
      p0[q] += zz * wa; p1[q] += zz * wb;
    }
  }
  #pragma unroll
  for (int off = 32; off >= 1; off >>= 1){
    #pragma unroll
    for (int q = 0; q < 4; ++q){ p0[q] += __shfl_xor(p0[q], off); p1[q] += __shfl_xor(p1[q], off); }
  }
  if (lane == 0){
    #pragma unroll
    for (int q = 0; q < 4; ++q){ redA[q][wv] = p0[q]; redB[q][wv] = p1[q]; }
  }
  __syncthreads();
  if (tid < 4){
    int q = tid;
    float l0 = redA[q][0] + redA[q][1] + redA[q][2] + redA[q][3] + b2[0];
    float l1 = redB[q][0] + redB[q][1] + redB[q][2] + redB[q][3] + b2[1];
    float mm = fmaxf(l0, l1);
    float e0 = expf(l0 - mm), e1 = expf(l1 - mm);
    float inv = 1.f / (e0 + e1);
    out[(size_t)(g0 + q) * 2 + 0] = e0 * inv;
    out[(size_t)(g0 + q) * 2 + 1] = e1 * inv;
  }
}

extern "C" void kernel_launch(void* const* d_in, const int* in_sizes, int n_in,
                              void* d_out, int out_size, void* d_ws, size_t ws_size,
                              hipStream_t stream){
  const float* x     = (const float*)d_in[0];
  const int*   ei    = (const int*)  d_in[1];
  const int*   batch = (const int*)  d_in[2];
  const float* g1w1  = (const float*)d_in[3];
  const float* g1b1  = (const float*)d_in[4];
  const float* g1w2  = (const float*)d_in[5];
  const float* g1b2  = (const float*)d_in[6];
  const float* g2w1  = (const float*)d_in[7];
  const float* g2b1  = (const float*)d_in[8];
  const float* g2w2  = (const float*)d_in[9];
  const float* g2b2  = (const float*)d_in[10];
  const float* lng   = (const float*)d_in[11];
  const float* lnb   = (const float*)d_in[12];
  const float* s2w1  = (const float*)d_in[13];
  const float* s2b1  = (const float*)d_in[14];
  const float* s2lng = (const float*)d_in[15];
  const float* s2lnb = (const float*)d_in[16];
  const float* s2w2  = (const float*)d_in[17];
  const float* s2b2  = (const float*)d_in[18];
  float* out = (float*)d_out;

  char* ws = (char*)d_ws;
  int*            rowptr = (int*)(ws + 0);                    //   800,032 B
  int*            col    = (int*)(ws + 800032);               // 3,200,000 B
  unsigned*       Gk     = (unsigned*)(ws + 4000032);         // 4,194,304 B (aliases 'cur')
  int*            cur    = (int*)Gk;
  unsigned short* W1T1   = (unsigned short*)(ws + 8194336);   //    65,536 B
  unsigned short* W2T1   = (unsigned short*)(ws + 8259872);   //   131,072 B
  unsigned short* W1T2   = (unsigned short*)(ws + 8390944);   //   131,072 B
  unsigned short* W2T2   = (unsigned short*)(ws + 8522016);   //   131,072 B
  unsigned short* H1     = (unsigned short*)(ws + 8653088);   // 102,400,000 B

  k_zero <<<(NN + 255) / 256, 256, 0, stream>>>(cur);
  k_count<<<NE / 256,         256, 0, stream>>>(ei, cur);
  k_scan <<<1,               1024, 0, stream>>>(cur, rowptr);
  k_fill <<<NE / 256,         256, 0, stream>>>(ei, rowptr, cur, col);
  k_initG<<<NG * HD / 256,    256, 0, stream>>>(Gk);
  k_wprep<<<128, 256, 0, stream>>>(g1w1, W1T1, 128);
  k_wprep<<<256, 256, 0, stream>>>(g1w2, W2T1, 256);
  k_wprep<<<256, 256, 0, stream>>>(g2w1, W1T2, 256);
  k_wprep<<<256, 256, 0, stream>>>(g2w2, W2T2, 256);
  k_layer1<<<NN / 32, 256, 0, stream>>>(x, rowptr, col, W1T1, g1b1, W2T1, g1b2, lng, lnb, H1);
  k_layer2<<<NN / 32, 256, 0, stream>>>(H1, rowptr, col, batch, W1T2, g2b1, W2T2, g2b2, Gk);
  head_kernel<<<NG / 4, 256, 0, stream>>>(Gk, s2w1, s2b1, s2lng, s2lnb, s2w2, s2b2, out);
}

// Round 5
// 916.385 us; speedup vs baseline: 2.7222x; 1.6251x over previous
//
#include <hip/hip_runtime.h>

#define NN 200000
#define NE 800000
#define NG 4096
#define AD 128
#define HD 256
#define LN_EPS 1e-5f
#define NB 782   // ceil(NN/256)

typedef __attribute__((ext_vector_type(8))) short     bf16x8;
typedef __attribute__((ext_vector_type(8))) unsigned short us8;
typedef __attribute__((ext_vector_type(4))) float     f32x4;

__device__ __forceinline__ float leaky(float v){ return v > 0.f ? v : 0.2f*v; }

__device__ __forceinline__ unsigned short f2bf(float f){
  unsigned u = __float_as_uint(f);
  return (unsigned short)((u + 0x7FFFu + ((u >> 16) & 1u)) >> 16);
}
__device__ __forceinline__ float bf2f(unsigned short h){ return __uint_as_float(((unsigned)h) << 16); }

__device__ __forceinline__ unsigned fkey(float f){
  unsigned u = __float_as_uint(f);
  return (u & 0x80000000u) ? ~u : (u | 0x80000000u);
}
__device__ __forceinline__ float fdec(unsigned k){
  return (k & 0x80000000u) ? __uint_as_float(k & 0x7FFFFFFFu) : __uint_as_float(~k);
}

// ---------------- CSR build ----------------
__global__ __launch_bounds__(256) void k_zero(int* __restrict__ cur){
  int i = blockIdx.x * 256 + threadIdx.x;
  if (i < NN) cur[i] = 0;
}

__global__ __launch_bounds__(256) void k_count(const int* __restrict__ ei, int* __restrict__ cur){
  int e = blockIdx.x * 256 + threadIdx.x;
  atomicAdd(&cur[ei[NE + e]], 1);
}

__global__ __launch_bounds__(256) void k_scanA(const int* __restrict__ cur, int* __restrict__ partial){
  __shared__ int sd[256];
  int t = threadIdx.x, b = blockIdx.x, i = b * 256 + t;
  sd[t] = (i < NN) ? cur[i] : 0;
  __syncthreads();
  for (int off = 128; off >= 1; off >>= 1){
    if (t < off) sd[t] += sd[t + off];
    __syncthreads();
  }
  if (t == 0) partial[b] = sd[0];
}

__global__ __launch_bounds__(1024) void k_scanB(const int* __restrict__ partial,
                                                int* __restrict__ scanoff, int* __restrict__ rowptr){
  __shared__ int sd[1024];
  int t = threadIdx.x;
  int v = (t < NB) ? partial[t] : 0;
  sd[t] = v; __syncthreads();
  for (int off = 1; off < 1024; off <<= 1){
    int u = (t >= off) ? sd[t - off] : 0;
    __syncthreads();
    sd[t] += u;
    __syncthreads();
  }
  if (t < NB) scanoff[t] = sd[t] - v;
  if (t == 0) rowptr[NN] = NE;
}

__global__ __launch_bounds__(256) void k_scanC(int* __restrict__ cur, const int* __restrict__ scanoff,
                                               int* __restrict__ rowptr){
  __shared__ int sd[256];
  int t = threadIdx.x, b = blockIdx.x, i = b * 256 + t;
  int v = (i < NN) ? cur[i] : 0;
  sd[t] = v; __syncthreads();
  for (int off = 1; off < 256; off <<= 1){
    int u = (t >= off) ? sd[t - off] : 0;
    __syncthreads();
    sd[t] += u;
    __syncthreads();
  }
  if (i < NN){ rowptr[i] = scanoff[b] + sd[t] - v; cur[i] = 0; }
}

__global__ __launch_bounds__(256) void k_fill(const int* __restrict__ ei,
                                              const int* __restrict__ rowptr,
                                              int* __restrict__ cur,
                                              int* __restrict__ col){
  int e = blockIdx.x * 256 + threadIdx.x;
  int s = ei[e], d = ei[NE + e];
  int pos = atomicAdd(&cur[d], 1);
  col[rowptr[d] + pos] = s;
}

__global__ __launch_bounds__(256) void k_initG(unsigned* __restrict__ Gk){
  int i = blockIdx.x * 256 + threadIdx.x;
  Gk[i] = 0x00800000u;                      // fkey(-FLT_MAX)
}

// weights: f32 [K][256] -> bf16 transposed [256][K]
__global__ __launch_bounds__(256) void k_wprep(const float* __restrict__ src,
                                               unsigned short* __restrict__ dst, int K){
  int k = blockIdx.x, n = threadIdx.x;
  dst[(size_t)n * K + k] = f2bf(src[(size_t)k * 256 + n]);
}

// ---------------- fused GIN layer 1: 16 rows/block, 16 thr/row gather, MFMA MLP, LN+leaky -> bf16 H1 ----------------
__global__ __launch_bounds__(256) void k_layer1(const float* __restrict__ x,
                                                const int* __restrict__ rowptr,
                                                const int* __restrict__ col,
                                                const unsigned short* __restrict__ W1T,  // [256][128]
                                                const float* __restrict__ b1,
                                                const unsigned short* __restrict__ W2T,  // [256][256]
                                                const float* __restrict__ b2,
                                                const float* __restrict__ lng,
                                                const float* __restrict__ lnb,
                                                unsigned short* __restrict__ H1){
  __shared__ alignas(16) char sS[16 * 256 + 16 * 512];   // zS 4KB | tS 8KB
  __shared__ float2 redS[16][4];
  char* zS = sS;
  char* tS = sS + 4096;
  const int tid = threadIdx.x;
  const int l = tid & 63, wv = tid >> 6;
  const int cl = l & 15, kg = l >> 4;
  const int row0 = blockIdx.x * 16;

  { // ---- gather: row per 16-thread group, thread owns 8 f32 cols ----
    const int row = tid >> 4, sub = tid & 15;
    const int grow = row0 + row;
    const float4* x4 = (const float4*)x;
    float4 s0 = x4[(size_t)grow * 32 + sub * 2];
    float4 s1 = x4[(size_t)grow * 32 + sub * 2 + 1];
    float a[8] = {s0.x, s0.y, s0.z, s0.w, s1.x, s1.y, s1.z, s1.w};
    const int p = rowptr[grow], pe = rowptr[grow + 1];
    int q = p;
    for (; q + 4 <= pe; q += 4){
      int j0 = col[q], j1 = col[q+1], j2 = col[q+2], j3 = col[q+3];
      float4 b00 = x4[(size_t)j0*32 + sub*2], b01 = x4[(size_t)j0*32 + sub*2 + 1];
      float4 b10 = x4[(size_t)j1*32 + sub*2], b11 = x4[(size_t)j1*32 + sub*2 + 1];
      float4 b20 = x4[(size_t)j2*32 + sub*2], b21 = x4[(size_t)j2*32 + sub*2 + 1];
      float4 b30 = x4[(size_t)j3*32 + sub*2], b31 = x4[(size_t)j3*32 + sub*2 + 1];
      a[0] += (b00.x + b10.x) + (b20.x + b30.x);
      a[1] += (b00.y + b10.y) + (b20.y + b30.y);
      a[2] += (b00.z + b10.z) + (b20.z + b30.z);
      a[3] += (b00.w + b10.w) + (b20.w + b30.w);
      a[4] += (b01.x + b11.x) + (b21.x + b31.x);
      a[5] += (b01.y + b11.y) + (b21.y + b31.y);
      a[6] += (b01.z + b11.z) + (b21.z + b31.z);
      a[7] += (b01.w + b11.w) + (b21.w + b31.w);
    }
    for (; q < pe; ++q){
      int j = col[q];
      float4 c0 = x4[(size_t)j*32 + sub*2], c1 = x4[(size_t)j*32 + sub*2 + 1];
      a[0]+=c0.x; a[1]+=c0.y; a[2]+=c0.z; a[3]+=c0.w;
      a[4]+=c1.x; a[5]+=c1.y; a[6]+=c1.z; a[7]+=c1.w;
    }
    us8 o;
    #pragma unroll
    for (int j = 0; j < 8; ++j) o[j] = f2bf(a[j]);
    *(us8*)&zS[row * 256 + ((sub * 16) ^ ((row & 7) << 4))] = o;
  }
  __syncthreads();

  // ---- GEMM-A: t = relu(z @ w1 + b1), K=128; wave owns 64-col strip ----
  f32x4 acc[4];
  #pragma unroll
  for (int nt = 0; nt < 4; ++nt){
    float bv = b1[wv * 64 + nt * 16 + cl];
    acc[nt] = (f32x4){bv, bv, bv, bv};
  }
  #pragma unroll
  for (int ks = 0; ks < 4; ++ks){
    const int kb = (ks * 32 + kg * 8) * 2;
    bf16x8 a0 = *(const bf16x8*)&zS[cl * 256 + (kb ^ ((cl & 7) << 4))];
    #pragma unroll
    for (int nt = 0; nt < 4; ++nt){
      bf16x8 b = *(const bf16x8*)(W1T + (size_t)(wv * 64 + nt * 16 + cl) * AD + ks * 32 + kg * 8);
      acc[nt] = __builtin_amdgcn_mfma_f32_16x16x32_bf16(a0, b, acc[nt], 0, 0, 0);
    }
  }
  #pragma unroll
  for (int nt = 0; nt < 4; ++nt)
    #pragma unroll
    for (int rg = 0; rg < 4; ++rg){
      float v = fmaxf(acc[nt][rg], 0.f);
      int row = kg * 4 + rg;
      int cc = wv * 64 + nt * 16 + cl;
      *(unsigned short*)&tS[row * 512 + ((cc * 2) ^ ((row & 7) << 4))] = f2bf(v);
    }
  __syncthreads();

  // ---- GEMM-B: h = t @ w2 + b2, K=256 ----
  #pragma unroll
  for (int nt = 0; nt < 4; ++nt){
    float bv = b2[wv * 64 + nt * 16 + cl];
    acc[nt] = (f32x4){bv, bv, bv, bv};
  }
  #pragma unroll
  for (int ks = 0; ks < 8; ++ks){
    const int kb = (ks * 32 + kg * 8) * 2;
    bf16x8 a0 = *(const bf16x8*)&tS[cl * 512 + (kb ^ ((cl & 7) << 4))];
    #pragma unroll
    for (int nt = 0; nt < 4; ++nt){
      bf16x8 b = *(const bf16x8*)(W2T + (size_t)(wv * 64 + nt * 16 + cl) * HD + ks * 32 + kg * 8);
      acc[nt] = __builtin_amdgcn_mfma_f32_16x16x32_bf16(a0, b, acc[nt], 0, 0, 0);
    }
  }

  // ---- LN(256) + leaky + bf16 store; row's cols span 4 waves -> LDS reduce ----
  float s1v[4], s2v[4];
  #pragma unroll
  for (int rg = 0; rg < 4; ++rg){
    float a = acc[0][rg] + acc[1][rg] + acc[2][rg] + acc[3][rg];
    float b = acc[0][rg]*acc[0][rg] + acc[1][rg]*acc[1][rg]
            + acc[2][rg]*acc[2][rg] + acc[3][rg]*acc[3][rg];
    #pragma unroll
    for (int off = 1; off <= 8; off <<= 1){ a += __shfl_xor(a, off); b += __shfl_xor(b, off); }
    s1v[rg] = a; s2v[rg] = b;
  }
  if (cl == 0){
    #pragma unroll
    for (int rg = 0; rg < 4; ++rg)
      redS[kg * 4 + rg][wv] = make_float2(s1v[rg], s2v[rg]);
  }
  __syncthreads();
  #pragma unroll
  for (int rg = 0; rg < 4; ++rg){
    int row = kg * 4 + rg;
    float t1 = redS[row][0].x + redS[row][1].x + redS[row][2].x + redS[row][3].x;
    float t2 = redS[row][0].y + redS[row][1].y + redS[row][2].y + redS[row][3].y;
    float m  = t1 * (1.f / HD);
    float vr = t2 * (1.f / HD) - m * m;
    float rs = rsqrtf(vr + LN_EPS);
    #pragma unroll
    for (int nt = 0; nt < 4; ++nt){
      int cc = wv * 64 + nt * 16 + cl;
      float v = (acc[nt][rg] - m) * rs * lng[cc] + lnb[cc];
      H1[(size_t)(row0 + row) * HD + cc] = f2bf(leaky(v));
    }
  }
}

// ---------------- fused GIN layer 2: gather -> MLP -> leaky -> block-segmented max -> few atomics ----------------
__global__ __launch_bounds__(256) void k_layer2(const unsigned short* __restrict__ H1,
                                                const int* __restrict__ rowptr,
                                                const int* __restrict__ col,
                                                const int* __restrict__ batch,
                                                const unsigned short* __restrict__ W1T,  // [256][256]
                                                const float* __restrict__ b1,
                                                const unsigned short* __restrict__ W2T,  // [256][256]
                                                const float* __restrict__ b2,
                                                unsigned* __restrict__ Gk){
  __shared__ alignas(16) char sS[16 * 512 * 2];   // zS 8KB | tS 8KB ; later overlaid by stageF 16KB
  char* zS = sS;
  char* tS = sS + 8192;
  float* stageF = (float*)sS;
  const int tid = threadIdx.x;
  const int l = tid & 63, wv = tid >> 6;
  const int cl = l & 15, kg = l >> 4;
  const int row0 = blockIdx.x * 16;

  { // ---- gather: thread owns 16 bf16 cols of one row ----
    const int row = tid >> 4, sub = tid & 15;
    const int grow = row0 + row;
    us8 a0 = *(const us8*)(H1 + (size_t)grow * HD + sub * 16);
    us8 a1 = *(const us8*)(H1 + (size_t)grow * HD + sub * 16 + 8);
    float a[16];
    #pragma unroll
    for (int j = 0; j < 8; ++j){ a[j] = bf2f(a0[j]); a[8 + j] = bf2f(a1[j]); }
    const int p = rowptr[grow], pe = rowptr[grow + 1];
    int q = p;
    for (; q + 4 <= pe; q += 4){
      int j0 = col[q], j1 = col[q+1], j2 = col[q+2], j3 = col[q+3];
      us8 b00 = *(const us8*)(H1 + (size_t)j0*HD + sub*16), b01 = *(const us8*)(H1 + (size_t)j0*HD + sub*16 + 8);
      us8 b10 = *(const us8*)(H1 + (size_t)j1*HD + sub*16), b11 = *(const us8*)(H1 + (size_t)j1*HD + sub*16 + 8);
      us8 b20 = *(const us8*)(H1 + (size_t)j2*HD + sub*16), b21 = *(const us8*)(H1 + (size_t)j2*HD + sub*16 + 8);
      us8 b30 = *(const us8*)(H1 + (size_t)j3*HD + sub*16), b31 = *(const us8*)(H1 + (size_t)j3*HD + sub*16 + 8);
      #pragma unroll
      for (int j = 0; j < 8; ++j){
        a[j]     += (bf2f(b00[j]) + bf2f(b10[j])) + (bf2f(b20[j]) + bf2f(b30[j]));
        a[8 + j] += (bf2f(b01[j]) + bf2f(b11[j])) + (bf2f(b21[j]) + bf2f(b31[j]));
      }
    }
    for (; q < pe; ++q){
      int jn = col[q];
      us8 c0 = *(const us8*)(H1 + (size_t)jn*HD + sub*16), c1 = *(const us8*)(H1 + (size_t)jn*HD + sub*16 + 8);
      #pragma unroll
      for (int j = 0; j < 8; ++j){ a[j] += bf2f(c0[j]); a[8 + j] += bf2f(c1[j]); }
    }
    us8 o0, o1;
    #pragma unroll
    for (int j = 0; j < 8; ++j){ o0[j] = f2bf(a[j]); o1[j] = f2bf(a[8 + j]); }
    const int swz = (row & 7) << 4;
    *(us8*)&zS[row * 512 + ((sub * 32) ^ swz)]      = o0;
    *(us8*)&zS[row * 512 + ((sub * 32 + 16) ^ swz)] = o1;
  }
  __syncthreads();

  // ---- GEMM-A: t = relu(z @ w1 + b1), K=256 ----
  f32x4 acc[4];
  #pragma unroll
  for (int nt = 0; nt < 4; ++nt){
    float bv = b1[wv * 64 + nt * 16 + cl];
    acc[nt] = (f32x4){bv, bv, bv, bv};
  }
  #pragma unroll
  for (int ks = 0; ks < 8; ++ks){
    const int kb = (ks * 32 + kg * 8) * 2;
    bf16x8 a0 = *(const bf16x8*)&zS[cl * 512 + (kb ^ ((cl & 7) << 4))];
    #pragma unroll
    for (int nt = 0; nt < 4; ++nt){
      bf16x8 b = *(const bf16x8*)(W1T + (size_t)(wv * 64 + nt * 16 + cl) * HD + ks * 32 + kg * 8);
      acc[nt] = __builtin_amdgcn_mfma_f32_16x16x32_bf16(a0, b, acc[nt], 0, 0, 0);
    }
  }
  #pragma unroll
  for (int nt = 0; nt < 4; ++nt)
    #pragma unroll
    for (int rg = 0; rg < 4; ++rg){
      float v = fmaxf(acc[nt][rg], 0.f);
      int row = kg * 4 + rg;
      int cc = wv * 64 + nt * 16 + cl;
      *(unsigned short*)&tS[row * 512 + ((cc * 2) ^ ((row & 7) << 4))] = f2bf(v);
    }
  __syncthreads();

  // ---- GEMM-B: h = t @ w2 + b2, K=256 ----
  #pragma unroll
  for (int nt = 0; nt < 4; ++nt){
    float bv = b2[wv * 64 + nt * 16 + cl];
    acc[nt] = (f32x4){bv, bv, bv, bv};
  }
  #pragma unroll
  for (int ks = 0; ks < 8; ++ks){
    const int kb = (ks * 32 + kg * 8) * 2;
    bf16x8 a0 = *(const bf16x8*)&tS[cl * 512 + (kb ^ ((cl & 7) << 4))];
    #pragma unroll
    for (int nt = 0; nt < 4; ++nt){
      bf16x8 b = *(const bf16x8*)(W2T + (size_t)(wv * 64 + nt * 16 + cl) * HD + ks * 32 + kg * 8);
      acc[nt] = __builtin_amdgcn_mfma_f32_16x16x32_bf16(a0, b, acc[nt], 0, 0, 0);
    }
  }
  __syncthreads();   // all ds_reads of zS/tS done -> safe to overlay stageF

  // ---- stage leaky(h) as f32 in LDS ----
  #pragma unroll
  for (int nt = 0; nt < 4; ++nt)
    #pragma unroll
    for (int rg = 0; rg < 4; ++rg){
      int row = kg * 4 + rg;
      int cc = wv * 64 + nt * 16 + cl;
      stageF[row * HD + cc] = leaky(acc[nt][rg]);
    }
  __syncthreads();

  // ---- segmented max over sorted batch: one thread per column, ~2 atomics/col ----
  {
    const int c = tid;    // 0..255
    int gprev = batch[row0];
    float m = -3.4e38f;
    #pragma unroll
    for (int r = 0; r < 16; ++r){
      int g = batch[row0 + r];
      if (g != gprev){
        atomicMax(&Gk[(size_t)gprev * HD + c], fkey(m));
        m = -3.4e38f;
        gprev = g;
      }
      m = fmaxf(m, stageF[r * HD + c]);
    }
    atomicMax(&Gk[(size_t)gprev * HD + c], fkey(m));
  }
}

// ---------------- head: 8 graphs per block ----------------
__global__ __launch_bounds__(256) void head_kernel(const unsigned* __restrict__ Gk,
                                                   const float* __restrict__ w1,
                                                   const float* __restrict__ b1,
                                                   const float* __restrict__ lng,
                                                   const float* __restrict__ lnb,
                                                   const float* __restrict__ w2,
                                                   const float* __restrict__ b2,
                                                   float* __restrict__ out){
  __shared__ float gs[8][256];
  __shared__ float redA[8][4], redB[8][4];
  const int tid = threadIdx.x;
  const int g0 = blockIdx.x * 8;
  #pragma unroll
  for (int q = 0; q < 8; ++q) gs[q][tid] = fdec(Gk[(size_t)(g0 + q) * 256 + tid]);
  __syncthreads();

  float z[8][3];
  #pragma unroll
  for (int j = 0; j < 3; ++j){
    const int c = tid + j * 256;
    float a[8];
    float bv = b1[c];
    #pragma unroll
    for (int q = 0; q < 8; ++q) a[q] = bv;
    #pragma unroll 8
    for (int k = 0; k < 256; ++k){
      float w = w1[(size_t)k * 768 + c];
      #pragma unroll
      for (int q = 0; q < 8; ++q) a[q] += gs[q][k] * w;
    }
    #pragma unroll
    for (int q = 0; q < 8; ++q) z[q][j] = a[q];
  }

  const int lane = tid & 63, wv = tid >> 6;
  float mean[8], rs[8];
  {
    float s1[8], s2[8];
    #pragma unroll
    for (int q = 0; q < 8; ++q){
      s1[q] = z[q][0] + z[q][1] + z[q][2];
      s2[q] = z[q][0]*z[q][0] + z[q][1]*z[q][1] + z[q][2]*z[q][2];
    }
    #pragma unroll
    for (int off = 32; off >= 1; off >>= 1){
      #pragma unroll
      for (int q = 0; q < 8; ++q){ s1[q] += __shfl_xor(s1[q], off); s2[q] += __shfl_xor(s2[q], off); }
    }
    if (lane == 0){
      #pragma unroll
      for (int q = 0; q < 8; ++q){ redA[q][wv] = s1[q]; redB[q][wv] = s2[q]; }
    }
    __syncthreads();
    #pragma unroll
    for (int q = 0; q < 8; ++q){
      float t1 = redA[q][0] + redA[q][1] + redA[q][2] + redA[q][3];
      float t2 = redB[q][0] + redB[q][1] + redB[q][2] + redB[q][3];
      float m = t1 * (1.f / 768.f);
      float v = t2 * (1.f / 768.f) - m * m;
      mean[q] = m; rs[q] = rsqrtf(v + LN_EPS);
    }
  }
  __syncthreads();

  float p0[8], p1[8];
  #pragma unroll
  for (int q = 0; q < 8; ++q){ p0[q] = 0.f; p1[q] = 0.f; }
  #pragma unroll
  for (int j = 0; j < 3; ++j){
    const int c = tid + j * 256;
    float gcol = lng[c], bcol = lnb[c];
    float wa = w2[2 * c], wb = w2[2 * c + 1];
    #pragma unroll
    for (int q = 0; q < 8; ++q){
      float zz = leaky((z[q][j] - mean[q]) * rs[q] * gcol + bcol);
      p0[q] += zz * wa; p1[q] += zz * wb;
    }
  }
  #pragma unroll
  for (int off = 32; off >= 1; off >>= 1){
    #pragma unroll
    for (int q = 0; q < 8; ++q){ p0[q] += __shfl_xor(p0[q], off); p1[q] += __shfl_xor(p1[q], off); }
  }
  if (lane == 0){
    #pragma unroll
    for (int q = 0; q < 8; ++q){ redA[q][wv] = p0[q]; redB[q][wv] = p1[q]; }
  }
  __syncthreads();
  if (tid < 8){
    int q = tid;
    float l0 = redA[q][0] + redA[q][1] + redA[q][2] + redA[q][3] + b2[0];
    float l1 = redB[q][0] + redB[q][1] + redB[q][2] + redB[q][3] + b2[1];
    float mm = fmaxf(l0, l1);
    float e0 = expf(l0 - mm), e1 = expf(l1 - mm);
    float inv = 1.f / (e0 + e1);
    out[(size_t)(g0 + q) * 2 + 0] = e0 * inv;
    out[(size_t)(g0 + q) * 2 + 1] = e1 * inv;
  }
}

extern "C" void kernel_launch(void* const* d_in, const int* in_sizes, int n_in,
                              void* d_out, int out_size, void* d_ws, size_t ws_size,
                              hipStream_t stream){
  const float* x     = (const float*)d_in[0];
  const int*   ei    = (const int*)  d_in[1];
  const int*   batch = (const int*)  d_in[2];
  const float* g1w1  = (const float*)d_in[3];
  const float* g1b1  = (const float*)d_in[4];
  const float* g1w2  = (const float*)d_in[5];
  const float* g1b2  = (const float*)d_in[6];
  const float* g2w1  = (const float*)d_in[7];
  const float* g2b1  = (const float*)d_in[8];
  const float* g2w2  = (const float*)d_in[9];
  const float* g2b2  = (const float*)d_in[10];
  const float* lng   = (const float*)d_in[11];
  const float* lnb   = (const float*)d_in[12];
  const float* s2w1  = (const float*)d_in[13];
  const float* s2b1  = (const float*)d_in[14];
  const float* s2lng = (const float*)d_in[15];
  const float* s2lnb = (const float*)d_in[16];
  const float* s2w2  = (const float*)d_in[17];
  const float* s2b2  = (const float*)d_in[18];
  float* out = (float*)d_out;

  // workspace: 111,061,280 B total (< 111.4 MB proven)
  char* ws = (char*)d_ws;
  int*            rowptr  = (int*)(ws + 0);                    //   800,032 B
  int*            col     = (int*)(ws + 800032);               // 3,200,000 B
  unsigned*       Gk      = (unsigned*)(ws + 4000032);         // 4,194,304 B (aliases 'cur')
  int*            cur     = (int*)Gk;
  unsigned short* W1T1    = (unsigned short*)(ws + 8194336);   //    65,536 B
  unsigned short* W2T1    = (unsigned short*)(ws + 8259872);   //   131,072 B
  unsigned short* W1T2    = (unsigned short*)(ws + 8390944);   //   131,072 B
  unsigned short* W2T2    = (unsigned short*)(ws + 8522016);   //   131,072 B
  int*            partial = (int*)(ws + 8653088);              //     4,096 B
  int*            scanoff = (int*)(ws + 8657184);              //     4,096 B
  unsigned short* H1      = (unsigned short*)(ws + 8661280);   // 102,400,000 B

  k_zero <<<(NN + 255) / 256, 256, 0, stream>>>(cur);
  k_count<<<NE / 256,         256, 0, stream>>>(ei, cur);
  k_scanA<<<NB,               256, 0, stream>>>(cur, partial);
  k_scanB<<<1,               1024, 0, stream>>>(partial, scanoff, rowptr);
  k_scanC<<<NB,               256, 0, stream>>>(cur, scanoff, rowptr);
  k_fill <<<NE / 256,         256, 0, stream>>>(ei, rowptr, cur, col);
  k_initG<<<NG * HD / 256,    256, 0, stream>>>(Gk);
  k_wprep<<<128, 256, 0, stream>>>(g1w1, W1T1, 128);
  k_wprep<<<256, 256, 0, stream>>>(g1w2, W2T1, 256);
  k_wprep<<<256, 256, 0, stream>>>(g2w1, W1T2, 256);
  k_wprep<<<256, 256, 0, stream>>>(g2w2, W2T2, 256);
  k_layer1<<<NN / 16, 256, 0, stream>>>(x, rowptr, col, W1T1, g1b1, W2T1, g1b2, lng, lnb, H1);
  k_layer2<<<NN / 16, 256, 0, stream>>>(H1, rowptr, col, batch, W1T2, g2b1, W2T2, g2b2, Gk);
  head_kernel<<<NG / 8, 256, 0, stream>>>(Gk, s2w1, s2b1, s2lng, s2lnb, s2w2, s2b2, out);
}